// Round 11
// baseline (58.386 us; speedup 1.0000x reference)
//
#include <hip/hip_runtime.h>
#include <stdint.h>

// Blocksparse Deep ReLU GAM forward via chained f16 MFMA.
// 128 towers, each 2->16->12->8->1 MLP over input pair (2t, 2t+1);
// out[s] = sum_t tower_t(x[s]) + bias. shape_loss output = zeros(128).
//
// v_mfma_f32_16x16x16_f16 D layout (row=(lane>>4)*4+reg, col=lane&15)
// equals the B layout (k=(lane>>4)*4+i, col=lane&15), so Y = W·X chains
// layer-to-layer with only lane-local relu + f32->f16 cvt.
//
// Round 11: NO LOCAL ARRAYS. r7-r10 all kept 84-295 MB/dispatch of
// scratch WRITE_SIZE at VGPR_Count=64: SROA runs before #pragma unroll,
// so b0[p*U+u] / accv[u] / h1v[j] looked runtime-indexed and the allocas
// were never promoted to registers (rule #20). Occupancy attributes
// (r10) were inert because the budget was never the problem. This
// version uses only named scalars: acc0..acc3, per-pack bq0..bq3, and a
// forceinline tower_chain() of named values. Everything is SSA.
//
// Kept: scalar L3 accumulate (C=0 MFMA, only row 0 nonzero -> += d3[0]),
// b1/b2 ride the L1/L2 C operands, out-zeroing folded into pack_frags.
//
// 4-tower shared B0: lane (kg,col) carries B0 rows 4kg..4kg+2 =
// {x[s][2(tb+kg)], x[s][2(tb+kg)+1], 1}; tower tb+j's A0 is nonzero only
// in k-columns 4j..4j+2, so one coalesced all-lane x load feeds 4 towers.
//
// Bias: b0 -> A0 k=4j+2 (homogeneous coord); b1 -> C of L1 MFMA;
// b2 -> C of L2 MFMA; sum_t b3[t] + bias -> one scalar at the end.

constexpr int BATCH = 32768;
constexpr int FEAT  = 256;
constexpr int NTOW  = 128;
constexpr int OUTN  = BATCH + NTOW;   // out + shape_loss

constexpr int REC = 544;  // dwords per tower record (2176 B, 16B-aligned)
// record layout (dword offsets): [0,512) = 64 lanes x 8 dwords
// {a0.lo,a0.hi,a1.lo,a1.hi,a2.lo,a2.hi,a3.lo,a3.hi};
// [512,528) = b1 f32[16]; [528,544) = b2 f32[16] (rows 8..15 = 0).
constexpr int OFF_B1 = 512, OFF_B2 = 528;

typedef _Float16 h4_t __attribute__((ext_vector_type(4)));
typedef __fp16   hp2_t __attribute__((ext_vector_type(2)));
typedef float    f4_t __attribute__((ext_vector_type(4)));

static __device__ __forceinline__ h4_t u2_to_h4(uint32_t lo, uint32_t hi) {
  union { uint2 u; h4_t h; } cv; cv.u.x = lo; cv.u.y = hi; return cv.h;
}
static __device__ __forceinline__ void h4_to_u2(h4_t v, uint32_t* d) {
  union { h4_t h; uint2 u; } cv; cv.h = v; d[0] = cv.u.x; d[1] = cv.u.y;
}
// pack 4 f32 -> 4 f16 (2x v_cvt_pkrtz) then packed relu (v_pk_max_f16 x2).
// relu(cvt(x)) == cvt(relu(x)): RTZ preserves sign; -0 is harmless in dots.
static __device__ __forceinline__ h4_t relu_pack4(const f4_t d) {
  const hp2_t lo = __builtin_amdgcn_cvt_pkrtz(d[0], d[1]);
  const hp2_t hi = __builtin_amdgcn_cvt_pkrtz(d[2], d[3]);
  h4_t r;
  r[0] = (_Float16)lo[0]; r[1] = (_Float16)lo[1];
  r[2] = (_Float16)hi[0]; r[3] = (_Float16)hi[1];
  const h4_t z = {(_Float16)0.f, (_Float16)0.f, (_Float16)0.f, (_Float16)0.f};
  return __builtin_elementwise_max(r, z);
}
// Build a B0 fragment from an x pair: {x0, x1, 1, 0}.
static __device__ __forceinline__ h4_t make_b0(const float* __restrict__ p) {
  const float2 xv = *(const float2*)p;
  const hp2_t xh = __builtin_amdgcn_cvt_pkrtz(xv.x, xv.y);
  h4_t b;
  b[0] = (_Float16)xh[0]; b[1] = (_Float16)xh[1];
  b[2] = (_Float16)1.0f;  b[3] = (_Float16)0.0f;
  return b;
}
// One tower's full 4-layer chain for one 16-sample tile; returns the
// lane's L3 output (only row 0 / reg 0 nonzero; other lanes return 0).
static __device__ __forceinline__ float tower_chain(
    h4_t a0, h4_t a1, h4_t a2, h4_t a3, f4_t c1, f4_t c2, h4_t b0) {
  const f4_t zc = {0.f, 0.f, 0.f, 0.f};
  const f4_t d0 = __builtin_amdgcn_mfma_f32_16x16x16f16(a0, b0, zc, 0, 0, 0);
  const h4_t h0 = relu_pack4(d0);
  const f4_t d1 = __builtin_amdgcn_mfma_f32_16x16x16f16(a1, h0, c1, 0, 0, 0);
  const h4_t h1 = relu_pack4(d1);
  const f4_t d2 = __builtin_amdgcn_mfma_f32_16x16x16f16(a2, h1, c2, 0, 0, 0);
  const h4_t h2 = relu_pack4(d2);
  const f4_t d3 = __builtin_amdgcn_mfma_f32_16x16x16f16(a3, h2, zc, 0, 0, 0);
  return d3[0];
}

__global__ void pack_frags(
    const float* __restrict__ W0, const float* __restrict__ B0,
    const float* __restrict__ W1, const float* __restrict__ B1,
    const float* __restrict__ W2, const float* __restrict__ B2,
    const float* __restrict__ W3, const float* __restrict__ B3,
    const float* __restrict__ bias, uint32_t* __restrict__ pack,
    float* __restrict__ out) {
  const int t   = blockIdx.x;
  const int l   = threadIdx.x;      // 64 threads = 64 lanes
  const int row = l & 15;           // A-frag row  = lane&15
  const int kg  = l >> 4;           // A-frag k    = (lane>>4)*4 + r
  uint32_t* rec = pack + t * REC;

  // Zero the output buffer (out[0:BATCH] accumulated by atomics;
  // shape_loss[BATCH:BATCH+NTOW] stays 0). Grid-stride over all blocks.
  for (int i = t * 64 + l; i < OUTN; i += NTOW * 64) out[i] = 0.f;

  h4_t a0, a1, a2, a3;
#pragma unroll
  for (int r = 0; r < 4; ++r) {
    const int k = kg * 4 + r;
    // A0: tower t occupies k-columns 4*(t&3) .. 4*(t&3)+2.
    float v0 = 0.f;
    if (kg == (t & 3)) {
      if (r < 2)       v0 = W0[(16*t + row) * FEAT + 2*t + r];
      else if (r == 2) v0 = B0[16*t + row];
    }
    a0[r] = (_Float16)v0;

    float v1 = 0.f;
    if (row < 12)    v1 = W1[(12*t + row) * (16*NTOW) + 16*t + k];
    a1[r] = (_Float16)v1;

    float v2 = 0.f;
    if (row < 8 && k < 12) v2 = W2[(8*t + row) * (12*NTOW) + 12*t + k];
    a2[r] = (_Float16)v2;

    float v3 = 0.f;
    if (row == 0 && k < 8) v3 = W3[t * (8*NTOW) + 8*t + k];
    a3[r] = (_Float16)v3;
  }
  uint32_t* lrec = rec + 8 * l;
  h4_to_u2(a0, lrec + 0);
  h4_to_u2(a1, lrec + 2);
  h4_to_u2(a2, lrec + 4);
  h4_to_u2(a3, lrec + 6);

  if (l < 16) {
    const float b1v = (l < 12) ? B1[12*t + l] : 0.f;
    rec[OFF_B1 + l] = __float_as_uint(b1v);
    const float b2v = (l < 8) ? B2[8*t + l] : 0.f;
    rec[OFF_B2 + l] = __float_as_uint(b2v);
  }
  if (t == 0 && l == 0) {
    float s = bias[0];
    for (int j = 0; j < NTOW; ++j) s += B3[j];
    pack[NTOW * REC] = __float_as_uint(s);
  }
}

// One wave: tower group g (16 towers), 4 tiles of 16 samples (64 samples).
__global__ __launch_bounds__(256) void bs_mfma(
    const float* __restrict__ x, const uint32_t* __restrict__ pack,
    float* __restrict__ out) {
  const int wid   = blockIdx.x * 4 + (threadIdx.x >> 6);
  const int lane  = threadIdx.x & 63;
  const int col   = lane & 15;       // sample within tile
  const int kg    = lane >> 4;
  const int g     = wid & 7;         // tower group: towers [16g, 16g+16)
  const int sbase = (wid >> 3) * 64;

  const float cbias = __uint_as_float(pack[NTOW * REC]);

  // Per-lane x base: sample row (sbase+col), feature 2*(16g + kg).
  const float* __restrict__ xb =
      x + (size_t)(sbase + col) * FEAT + 2 * (g * 16 + kg);

  const uint32_t* __restrict__ fp  = pack + (size_t)(g * 16) * REC + 8 * lane;
  const uint32_t* __restrict__ bp1 = pack + (size_t)(g * 16) * REC + OFF_B1 + kg * 4;
  const uint32_t* __restrict__ bp2 = pack + (size_t)(g * 16) * REC + OFF_B2 + kg * 4;

  float acc0 = 0.f, acc1 = 0.f, acc2 = 0.f, acc3 = 0.f;

#pragma unroll
  for (int p = 0; p < 4; ++p) {      // packs of 4 towers
    // Named B0 fragments for this pack's 4 sample tiles (shared by the
    // pack's 4 towers). No arrays -> guaranteed register allocation.
    const h4_t bq0 = make_b0(xb + 8 * p + (size_t)0 * 16 * FEAT);
    const h4_t bq1 = make_b0(xb + 8 * p + (size_t)1 * 16 * FEAT);
    const h4_t bq2 = make_b0(xb + 8 * p + (size_t)2 * 16 * FEAT);
    const h4_t bq3 = make_b0(xb + 8 * p + (size_t)3 * 16 * FEAT);

#pragma unroll
    for (int jj = 0; jj < 4; ++jj) {
      const int j = 4 * p + jj;
      const uint4  w01 = *(const uint4*)(fp + j * REC);      // a0|a1
      const uint4  w23 = *(const uint4*)(fp + j * REC + 4);  // a2|a3
      const float4 bb1 = *(const float4*)(bp1 + j * REC);
      const float4 bb2 = *(const float4*)(bp2 + j * REC);

      const h4_t a0 = u2_to_h4(w01.x, w01.y);
      const h4_t a1 = u2_to_h4(w01.z, w01.w);
      const h4_t a2 = u2_to_h4(w23.x, w23.y);
      const h4_t a3 = u2_to_h4(w23.z, w23.w);
      const f4_t c1 = {bb1.x, bb1.y, bb1.z, bb1.w};
      const f4_t c2 = {bb2.x, bb2.y, bb2.z, bb2.w};

      acc0 += tower_chain(a0, a1, a2, a3, c1, c2, bq0);
      acc1 += tower_chain(a0, a1, a2, a3, c1, c2, bq1);
      acc2 += tower_chain(a0, a1, a2, a3, c1, c2, bq2);
      acc3 += tower_chain(a0, a1, a2, a3, c1, c2, bq3);
    }
  }

  if (kg == 0) {
    const float add = (g == 0) ? cbias : 0.f;
    atomicAdd(out + sbase +  0 + col, acc0 + add);
    atomicAdd(out + sbase + 16 + col, acc1 + add);
    atomicAdd(out + sbase + 32 + col, acc2 + add);
    atomicAdd(out + sbase + 48 + col, acc3 + add);
  }
}

// ---- correctness-only fallback (ws too small; never expected) ----
__device__ __forceinline__ float gather_weight(
    int t, int i,
    const float* __restrict__ W0, const float* __restrict__ B0,
    const float* __restrict__ W1, const float* __restrict__ B1,
    const float* __restrict__ W2, const float* __restrict__ B2,
    const float* __restrict__ W3, const float* __restrict__ B3) {
  float v = 0.f;
  if (i < 32)       { int r = i >> 1, c = i & 1;               v = W0[(16*t + r)*FEAT + 2*t + c]; }
  else if (i < 48)  {                                           v = B0[16*t + (i - 32)]; }
  else if (i < 240) { int k = i - 48, r = k >> 4, c = k & 15;   v = W1[(12*t + r)*(16*NTOW) + 16*t + c]; }
  else if (i < 252) {                                           v = B1[12*t + (i - 240)]; }
  else if (i < 348) { int k = i - 252, r = k / 12, c = k - 12*r; v = W2[(8*t + r)*(12*NTOW) + 12*t + c]; }
  else if (i < 356) {                                           v = B2[8*t + (i - 348)]; }
  else if (i < 364) {                                           v = W3[t*(8*NTOW) + 8*t + (i - 356)]; }
  else if (i == 364){                                           v = B3[t]; }
  return v;
}

__global__ void bs_fwd_slow(
    const float* __restrict__ x,
    const float* __restrict__ W0, const float* __restrict__ B0,
    const float* __restrict__ W1, const float* __restrict__ B1,
    const float* __restrict__ W2, const float* __restrict__ B2,
    const float* __restrict__ W3, const float* __restrict__ B3,
    const float* __restrict__ bias,
    float* __restrict__ out) {
  const int s = blockIdx.x * blockDim.x + threadIdx.x;
  if (s >= BATCH) return;
  float acc = bias[0];
  for (int t = 0; t < NTOW; ++t) {
    float h0[16], h1[12], h2[8];
    const float x0 = x[(size_t)s*FEAT + 2*t], x1 = x[(size_t)s*FEAT + 2*t + 1];
    for (int r = 0; r < 16; ++r)
      h0[r] = fmaxf(0.f, gather_weight(t, 2*r, W0,B0,W1,B1,W2,B2,W3,B3) * x0
                        + gather_weight(t, 2*r+1, W0,B0,W1,B1,W2,B2,W3,B3) * x1
                        + gather_weight(t, 32+r, W0,B0,W1,B1,W2,B2,W3,B3));
    for (int r = 0; r < 12; ++r) {
      float sum = gather_weight(t, 240+r, W0,B0,W1,B1,W2,B2,W3,B3);
      for (int c = 0; c < 16; ++c)
        sum += gather_weight(t, 48+16*r+c, W0,B0,W1,B1,W2,B2,W3,B3) * h0[c];
      h1[r] = fmaxf(0.f, sum);
    }
    for (int r = 0; r < 8; ++r) {
      float sum = gather_weight(t, 348+r, W0,B0,W1,B1,W2,B2,W3,B3);
      for (int c = 0; c < 12; ++c)
        sum += gather_weight(t, 252+12*r+c, W0,B0,W1,B1,W2,B2,W3,B3) * h1[c];
      h2[r] = fmaxf(0.f, sum);
    }
    float sum = gather_weight(t, 364, W0,B0,W1,B1,W2,B2,W3,B3);
    for (int c = 0; c < 8; ++c)
      sum += gather_weight(t, 356+c, W0,B0,W1,B1,W2,B2,W3,B3) * h2[c];
    acc += sum;
  }
  out[s] = acc;
}

extern "C" void kernel_launch(void* const* d_in, const int* in_sizes, int n_in,
                              void* d_out, int out_size, void* d_ws, size_t ws_size,
                              hipStream_t stream) {
  const float* x    = (const float*)d_in[0];
  const float* W0   = (const float*)d_in[1];
  const float* B0   = (const float*)d_in[2];
  const float* W1   = (const float*)d_in[3];
  const float* B1   = (const float*)d_in[4];
  const float* W2   = (const float*)d_in[5];
  const float* B2   = (const float*)d_in[6];
  const float* W3   = (const float*)d_in[7];
  const float* B3   = (const float*)d_in[8];
  const float* bias = (const float*)d_in[9];
  float* out = (float*)d_out;

  const size_t packBytes = ((size_t)NTOW * REC + 1) * sizeof(uint32_t);

  if (ws_size >= packBytes) {
    uint32_t* pack = (uint32_t*)d_ws;
    // pack_frags also zeroes out[] (atomics accumulate; shape_loss stays 0).
    pack_frags<<<NTOW, 64, 0, stream>>>(W0, B0, W1, B1, W2, B2, W3, B3, bias, pack, out);
    const int waves = (BATCH / 64) * 8;           // 4096 waves
    bs_mfma<<<waves / 4, 256, 0, stream>>>(x, pack, out);
  } else {
    (void)hipMemsetAsync(d_out, 0, (size_t)out_size * sizeof(float), stream);
    bs_fwd_slow<<<BATCH / 256, 256, 0, stream>>>(x, W0, B0, W1, B1, W2, B2, W3, B3, bias, out);
  }
}

// Round 12
// 35.721 us; speedup vs baseline: 1.6345x; 1.6345x over previous
//
#include <hip/hip_runtime.h>
#include <stdint.h>

// Blocksparse Deep ReLU GAM forward via chained f16 MFMA.
// 128 towers, each 2->16->12->8->1 MLP over input pair (2t, 2t+1);
// out[s] = sum_t tower_t(x[s]) + bias. shape_loss output = zeros(128).
//
// v_mfma_f32_16x16x16_f16 D layout (row=(lane>>4)*4+reg, col=lane&15)
// equals the B layout (k=(lane>>4)*4+i, col=lane&15), so Y = W·X chains
// layer-to-layer with only lane-local relu + f32->f16 cvt.
//
// Round 12: bound liveness. r11 (all-SSA, fully unrolled) fixed the
// scratch spill (WRITE 84MB->1MB) but the scheduler hoisted all 16
// towers' loads -> 200 VGPR -> 2 waves/SIMD -> 54us. This version:
//  - outer pack loop '#pragma unroll 1' (4 rolled iterations): loads
//    can only be hoisted within one pack (4 towers x 16 VGPR in
//    flight), liveness ~110 VGPR;
//  - __launch_bounds__(256,4): hard 128-VGPR cap -> 4 waves/SIMD;
//  - inner 4-tower loop fully unrolled: 16 independent MFMA chains per
//    body for ILP; all values named scalars (no arrays -> no scratch).
//
// Kept: scalar L3 accumulate (C=0 MFMA, only row 0 nonzero -> += d3[0]),
// b1/b2 ride the L1/L2 C operands, out-zeroing folded into pack_frags.
//
// 4-tower shared B0: lane (kg,col) carries B0 rows 4kg..4kg+2 =
// {x[s][2(tb+kg)], x[s][2(tb+kg)+1], 1}; tower tb+j's A0 is nonzero only
// in k-columns 4j..4j+2, so one coalesced all-lane x load feeds 4 towers.
//
// Bias: b0 -> A0 k=4j+2 (homogeneous coord); b1 -> C of L1 MFMA;
// b2 -> C of L2 MFMA; sum_t b3[t] + bias -> one scalar at the end.

constexpr int BATCH = 32768;
constexpr int FEAT  = 256;
constexpr int NTOW  = 128;
constexpr int OUTN  = BATCH + NTOW;   // out + shape_loss

constexpr int REC = 544;  // dwords per tower record (2176 B, 16B-aligned)
// record layout (dword offsets): [0,512) = 64 lanes x 8 dwords
// {a0.lo,a0.hi,a1.lo,a1.hi,a2.lo,a2.hi,a3.lo,a3.hi};
// [512,528) = b1 f32[16]; [528,544) = b2 f32[16] (rows 8..15 = 0).
constexpr int OFF_B1 = 512, OFF_B2 = 528;

typedef _Float16 h4_t __attribute__((ext_vector_type(4)));
typedef __fp16   hp2_t __attribute__((ext_vector_type(2)));
typedef float    f4_t __attribute__((ext_vector_type(4)));

static __device__ __forceinline__ h4_t u2_to_h4(uint32_t lo, uint32_t hi) {
  union { uint2 u; h4_t h; } cv; cv.u.x = lo; cv.u.y = hi; return cv.h;
}
static __device__ __forceinline__ void h4_to_u2(h4_t v, uint32_t* d) {
  union { h4_t h; uint2 u; } cv; cv.h = v; d[0] = cv.u.x; d[1] = cv.u.y;
}
// pack 4 f32 -> 4 f16 (2x v_cvt_pkrtz) then packed relu (v_pk_max_f16 x2).
// relu(cvt(x)) == cvt(relu(x)): RTZ preserves sign; -0 is harmless in dots.
static __device__ __forceinline__ h4_t relu_pack4(const f4_t d) {
  const hp2_t lo = __builtin_amdgcn_cvt_pkrtz(d[0], d[1]);
  const hp2_t hi = __builtin_amdgcn_cvt_pkrtz(d[2], d[3]);
  h4_t r;
  r[0] = (_Float16)lo[0]; r[1] = (_Float16)lo[1];
  r[2] = (_Float16)hi[0]; r[3] = (_Float16)hi[1];
  const h4_t z = {(_Float16)0.f, (_Float16)0.f, (_Float16)0.f, (_Float16)0.f};
  return __builtin_elementwise_max(r, z);
}
// Build a B0 fragment from an x pair: {x0, x1, 1, 0}.
static __device__ __forceinline__ h4_t make_b0(const float* __restrict__ p) {
  const float2 xv = *(const float2*)p;
  const hp2_t xh = __builtin_amdgcn_cvt_pkrtz(xv.x, xv.y);
  h4_t b;
  b[0] = (_Float16)xh[0]; b[1] = (_Float16)xh[1];
  b[2] = (_Float16)1.0f;  b[3] = (_Float16)0.0f;
  return b;
}
// One tower's full 4-layer chain for one 16-sample tile; returns the
// lane's L3 output (only row 0 / reg 0 nonzero; other lanes return 0).
static __device__ __forceinline__ float tower_chain(
    h4_t a0, h4_t a1, h4_t a2, h4_t a3, f4_t c1, f4_t c2, h4_t b0) {
  const f4_t zc = {0.f, 0.f, 0.f, 0.f};
  const f4_t d0 = __builtin_amdgcn_mfma_f32_16x16x16f16(a0, b0, zc, 0, 0, 0);
  const h4_t h0 = relu_pack4(d0);
  const f4_t d1 = __builtin_amdgcn_mfma_f32_16x16x16f16(a1, h0, c1, 0, 0, 0);
  const h4_t h1 = relu_pack4(d1);
  const f4_t d2 = __builtin_amdgcn_mfma_f32_16x16x16f16(a2, h1, c2, 0, 0, 0);
  const h4_t h2 = relu_pack4(d2);
  const f4_t d3 = __builtin_amdgcn_mfma_f32_16x16x16f16(a3, h2, zc, 0, 0, 0);
  return d3[0];
}

__global__ void pack_frags(
    const float* __restrict__ W0, const float* __restrict__ B0,
    const float* __restrict__ W1, const float* __restrict__ B1,
    const float* __restrict__ W2, const float* __restrict__ B2,
    const float* __restrict__ W3, const float* __restrict__ B3,
    const float* __restrict__ bias, uint32_t* __restrict__ pack,
    float* __restrict__ out) {
  const int t   = blockIdx.x;
  const int l   = threadIdx.x;      // 64 threads = 64 lanes
  const int row = l & 15;           // A-frag row  = lane&15
  const int kg  = l >> 4;           // A-frag k    = (lane>>4)*4 + r
  uint32_t* rec = pack + t * REC;

  // Zero the output buffer (out[0:BATCH] accumulated by atomics;
  // shape_loss[BATCH:BATCH+NTOW] stays 0). Grid-stride over all blocks.
  for (int i = t * 64 + l; i < OUTN; i += NTOW * 64) out[i] = 0.f;

  h4_t a0, a1, a2, a3;
#pragma unroll
  for (int r = 0; r < 4; ++r) {
    const int k = kg * 4 + r;
    // A0: tower t occupies k-columns 4*(t&3) .. 4*(t&3)+2.
    float v0 = 0.f;
    if (kg == (t & 3)) {
      if (r < 2)       v0 = W0[(16*t + row) * FEAT + 2*t + r];
      else if (r == 2) v0 = B0[16*t + row];
    }
    a0[r] = (_Float16)v0;

    float v1 = 0.f;
    if (row < 12)    v1 = W1[(12*t + row) * (16*NTOW) + 16*t + k];
    a1[r] = (_Float16)v1;

    float v2 = 0.f;
    if (row < 8 && k < 12) v2 = W2[(8*t + row) * (12*NTOW) + 12*t + k];
    a2[r] = (_Float16)v2;

    float v3 = 0.f;
    if (row == 0 && k < 8) v3 = W3[t * (8*NTOW) + 8*t + k];
    a3[r] = (_Float16)v3;
  }
  uint32_t* lrec = rec + 8 * l;
  h4_to_u2(a0, lrec + 0);
  h4_to_u2(a1, lrec + 2);
  h4_to_u2(a2, lrec + 4);
  h4_to_u2(a3, lrec + 6);

  if (l < 16) {
    const float b1v = (l < 12) ? B1[12*t + l] : 0.f;
    rec[OFF_B1 + l] = __float_as_uint(b1v);
    const float b2v = (l < 8) ? B2[8*t + l] : 0.f;
    rec[OFF_B2 + l] = __float_as_uint(b2v);
  }
  if (t == 0 && l == 0) {
    float s = bias[0];
    for (int j = 0; j < NTOW; ++j) s += B3[j];
    pack[NTOW * REC] = __float_as_uint(s);
  }
}

// One wave: tower group g (16 towers), 4 tiles of 16 samples (64 samples).
__global__ __launch_bounds__(256, 4) void bs_mfma(
    const float* __restrict__ x, const uint32_t* __restrict__ pack,
    float* __restrict__ out) {
  const int wid   = blockIdx.x * 4 + (threadIdx.x >> 6);
  const int lane  = threadIdx.x & 63;
  const int col   = lane & 15;       // sample within tile
  const int kg    = lane >> 4;
  const int g     = wid & 7;         // tower group: towers [16g, 16g+16)
  const int sbase = (wid >> 3) * 64;

  const float cbias = __uint_as_float(pack[NTOW * REC]);

  // Per-lane x base: sample row (sbase+col), feature 2*(16g + kg).
  const float* __restrict__ xb =
      x + (size_t)(sbase + col) * FEAT + 2 * (g * 16 + kg);

  const uint32_t* __restrict__ fp  = pack + (size_t)(g * 16) * REC + 8 * lane;
  const uint32_t* __restrict__ bp1 = pack + (size_t)(g * 16) * REC + OFF_B1 + kg * 4;
  const uint32_t* __restrict__ bp2 = pack + (size_t)(g * 16) * REC + OFF_B2 + kg * 4;

  float acc0 = 0.f, acc1 = 0.f, acc2 = 0.f, acc3 = 0.f;

#pragma unroll 1
  for (int p = 0; p < 4; ++p) {      // packs of 4 towers — ROLLED
    // Named B0 fragments for this pack's 4 sample tiles (shared by the
    // pack's 4 towers). Named scalars -> guaranteed register allocation.
    const float* __restrict__ xp = xb + 8 * p;
    const h4_t bq0 = make_b0(xp + (size_t)0 * 16 * FEAT);
    const h4_t bq1 = make_b0(xp + (size_t)1 * 16 * FEAT);
    const h4_t bq2 = make_b0(xp + (size_t)2 * 16 * FEAT);
    const h4_t bq3 = make_b0(xp + (size_t)3 * 16 * FEAT);

    const uint32_t* __restrict__ fpp  = fp  + (size_t)(4 * p) * REC;
    const uint32_t* __restrict__ bpp1 = bp1 + (size_t)(4 * p) * REC;
    const uint32_t* __restrict__ bpp2 = bp2 + (size_t)(4 * p) * REC;

#pragma unroll
    for (int jj = 0; jj < 4; ++jj) { // towers within pack — UNROLLED
      const uint4  w01 = *(const uint4*)(fpp + jj * REC);      // a0|a1
      const uint4  w23 = *(const uint4*)(fpp + jj * REC + 4);  // a2|a3
      const float4 bb1 = *(const float4*)(bpp1 + jj * REC);
      const float4 bb2 = *(const float4*)(bpp2 + jj * REC);

      const h4_t a0 = u2_to_h4(w01.x, w01.y);
      const h4_t a1 = u2_to_h4(w01.z, w01.w);
      const h4_t a2 = u2_to_h4(w23.x, w23.y);
      const h4_t a3 = u2_to_h4(w23.z, w23.w);
      const f4_t c1 = {bb1.x, bb1.y, bb1.z, bb1.w};
      const f4_t c2 = {bb2.x, bb2.y, bb2.z, bb2.w};

      acc0 += tower_chain(a0, a1, a2, a3, c1, c2, bq0);
      acc1 += tower_chain(a0, a1, a2, a3, c1, c2, bq1);
      acc2 += tower_chain(a0, a1, a2, a3, c1, c2, bq2);
      acc3 += tower_chain(a0, a1, a2, a3, c1, c2, bq3);
    }
  }

  if (kg == 0) {
    const float add = (g == 0) ? cbias : 0.f;
    atomicAdd(out + sbase +  0 + col, acc0 + add);
    atomicAdd(out + sbase + 16 + col, acc1 + add);
    atomicAdd(out + sbase + 32 + col, acc2 + add);
    atomicAdd(out + sbase + 48 + col, acc3 + add);
  }
}

// ---- correctness-only fallback (ws too small; never expected) ----
__device__ __forceinline__ float gather_weight(
    int t, int i,
    const float* __restrict__ W0, const float* __restrict__ B0,
    const float* __restrict__ W1, const float* __restrict__ B1,
    const float* __restrict__ W2, const float* __restrict__ B2,
    const float* __restrict__ W3, const float* __restrict__ B3) {
  float v = 0.f;
  if (i < 32)       { int r = i >> 1, c = i & 1;               v = W0[(16*t + r)*FEAT + 2*t + c]; }
  else if (i < 48)  {                                           v = B0[16*t + (i - 32)]; }
  else if (i < 240) { int k = i - 48, r = k >> 4, c = k & 15;   v = W1[(12*t + r)*(16*NTOW) + 16*t + c]; }
  else if (i < 252) {                                           v = B1[12*t + (i - 240)]; }
  else if (i < 348) { int k = i - 252, r = k / 12, c = k - 12*r; v = W2[(8*t + r)*(12*NTOW) + 12*t + c]; }
  else if (i < 356) {                                           v = B2[8*t + (i - 348)]; }
  else if (i < 364) {                                           v = W3[t*(8*NTOW) + 8*t + (i - 356)]; }
  else if (i == 364){                                           v = B3[t]; }
  return v;
}

__global__ void bs_fwd_slow(
    const float* __restrict__ x,
    const float* __restrict__ W0, const float* __restrict__ B0,
    const float* __restrict__ W1, const float* __restrict__ B1,
    const float* __restrict__ W2, const float* __restrict__ B2,
    const float* __restrict__ W3, const float* __restrict__ B3,
    const float* __restrict__ bias,
    float* __restrict__ out) {
  const int s = blockIdx.x * blockDim.x + threadIdx.x;
  if (s >= BATCH) return;
  float acc = bias[0];
  for (int t = 0; t < NTOW; ++t) {
    float h0[16], h1[12], h2[8];
    const float x0 = x[(size_t)s*FEAT + 2*t], x1 = x[(size_t)s*FEAT + 2*t + 1];
    for (int r = 0; r < 16; ++r)
      h0[r] = fmaxf(0.f, gather_weight(t, 2*r, W0,B0,W1,B1,W2,B2,W3,B3) * x0
                        + gather_weight(t, 2*r+1, W0,B0,W1,B1,W2,B2,W3,B3) * x1
                        + gather_weight(t, 32+r, W0,B0,W1,B1,W2,B2,W3,B3));
    for (int r = 0; r < 12; ++r) {
      float sum = gather_weight(t, 240+r, W0,B0,W1,B1,W2,B2,W3,B3);
      for (int c = 0; c < 16; ++c)
        sum += gather_weight(t, 48+16*r+c, W0,B0,W1,B1,W2,B2,W3,B3) * h0[c];
      h1[r] = fmaxf(0.f, sum);
    }
    for (int r = 0; r < 8; ++r) {
      float sum = gather_weight(t, 348+r, W0,B0,W1,B1,W2,B2,W3,B3);
      for (int c = 0; c < 12; ++c)
        sum += gather_weight(t, 252+12*r+c, W0,B0,W1,B1,W2,B2,W3,B3) * h1[c];
      h2[r] = fmaxf(0.f, sum);
    }
    float sum = gather_weight(t, 364, W0,B0,W1,B1,W2,B2,W3,B3);
    for (int c = 0; c < 8; ++c)
      sum += gather_weight(t, 356+c, W0,B0,W1,B1,W2,B2,W3,B3) * h2[c];
    acc += sum;
  }
  out[s] = acc;
}

extern "C" void kernel_launch(void* const* d_in, const int* in_sizes, int n_in,
                              void* d_out, int out_size, void* d_ws, size_t ws_size,
                              hipStream_t stream) {
  const float* x    = (const float*)d_in[0];
  const float* W0   = (const float*)d_in[1];
  const float* B0   = (const float*)d_in[2];
  const float* W1   = (const float*)d_in[3];
  const float* B1   = (const float*)d_in[4];
  const float* W2   = (const float*)d_in[5];
  const float* B2   = (const float*)d_in[6];
  const float* W3   = (const float*)d_in[7];
  const float* B3   = (const float*)d_in[8];
  const float* bias = (const float*)d_in[9];
  float* out = (float*)d_out;

  const size_t packBytes = ((size_t)NTOW * REC + 1) * sizeof(uint32_t);

  if (ws_size >= packBytes) {
    uint32_t* pack = (uint32_t*)d_ws;
    // pack_frags also zeroes out[] (atomics accumulate; shape_loss stays 0).
    pack_frags<<<NTOW, 64, 0, stream>>>(W0, B0, W1, B1, W2, B2, W3, B3, bias, pack, out);
    const int waves = (BATCH / 64) * 8;           // 4096 waves
    bs_mfma<<<waves / 4, 256, 0, stream>>>(x, pack, out);
  } else {
    (void)hipMemsetAsync(d_out, 0, (size_t)out_size * sizeof(float), stream);
    bs_fwd_slow<<<BATCH / 256, 256, 0, stream>>>(x, W0, B0, W1, B1, W2, B2, W3, B3, bias, out);
  }
}

// Round 13
// 31.153 us; speedup vs baseline: 1.8742x; 1.1467x over previous
//
#include <hip/hip_runtime.h>
#include <stdint.h>

// Blocksparse Deep ReLU GAM forward via chained f16 MFMA.
// 128 towers, each 2->16->12->8->1 MLP over input pair (2t, 2t+1);
// out[s] = sum_t tower_t(x[s]) + bias. shape_loss output = zeros(128).
//
// v_mfma_f32_16x16x16_f16 D layout (row=(lane>>4)*4+reg, col=lane&15)
// equals the B layout (k=(lane>>4)*4+i, col=lane&15), so Y = W·X chains
// layer-to-layer with only lane-local relu + f32->f16 cvt.
//
// Round 13: same-g blocks. r12's wid&7 mapping gave each block's 4
// waves 4 DIFFERENT tower groups -> a CU's waves touch all 765 KB of
// records -> every rolled-loop weight load is an L2 (~200cy) miss.
// Now g = blockIdx&7: all 4 waves in a block stream the SAME 16
// records (34.8 KB ~ L1), so waves 1-3 hit L1 (~30cy) and L2 read
// traffic drops ~4x. Everything else is r12's proven structure:
//  - outer pack loop '#pragma unroll 1' bounds liveness (~110 VGPR);
//  - __launch_bounds__(256,4): 128-VGPR cap, 4 waves/SIMD;
//  - named scalars only (arrays -> scratch, rule #20; r8-r10 lesson);
//  - scalar L3 accumulate, b1/b2 ride L1/L2 C operands, out-zeroing
//    folded into pack_frags.
//
// 4-tower shared B0: lane (kg,col) carries B0 rows 4kg..4kg+2 =
// {x[s][2(tb+kg)], x[s][2(tb+kg)+1], 1}; tower tb+j's A0 is nonzero only
// in k-columns 4j..4j+2, so one coalesced all-lane x load feeds 4 towers.
//
// Bias: b0 -> A0 k=4j+2 (homogeneous coord); b1 -> C of L1 MFMA;
// b2 -> C of L2 MFMA; sum_t b3[t] + bias -> one scalar at the end.

constexpr int BATCH = 32768;
constexpr int FEAT  = 256;
constexpr int NTOW  = 128;
constexpr int OUTN  = BATCH + NTOW;   // out + shape_loss

constexpr int REC = 544;  // dwords per tower record (2176 B, 16B-aligned)
// record layout (dword offsets): [0,512) = 64 lanes x 8 dwords
// {a0.lo,a0.hi,a1.lo,a1.hi,a2.lo,a2.hi,a3.lo,a3.hi};
// [512,528) = b1 f32[16]; [528,544) = b2 f32[16] (rows 8..15 = 0).
constexpr int OFF_B1 = 512, OFF_B2 = 528;

typedef _Float16 h4_t __attribute__((ext_vector_type(4)));
typedef __fp16   hp2_t __attribute__((ext_vector_type(2)));
typedef float    f4_t __attribute__((ext_vector_type(4)));

static __device__ __forceinline__ h4_t u2_to_h4(uint32_t lo, uint32_t hi) {
  union { uint2 u; h4_t h; } cv; cv.u.x = lo; cv.u.y = hi; return cv.h;
}
static __device__ __forceinline__ void h4_to_u2(h4_t v, uint32_t* d) {
  union { h4_t h; uint2 u; } cv; cv.h = v; d[0] = cv.u.x; d[1] = cv.u.y;
}
// pack 4 f32 -> 4 f16 (2x v_cvt_pkrtz) then packed relu (v_pk_max_f16 x2).
// relu(cvt(x)) == cvt(relu(x)): RTZ preserves sign; -0 is harmless in dots.
static __device__ __forceinline__ h4_t relu_pack4(const f4_t d) {
  const hp2_t lo = __builtin_amdgcn_cvt_pkrtz(d[0], d[1]);
  const hp2_t hi = __builtin_amdgcn_cvt_pkrtz(d[2], d[3]);
  h4_t r;
  r[0] = (_Float16)lo[0]; r[1] = (_Float16)lo[1];
  r[2] = (_Float16)hi[0]; r[3] = (_Float16)hi[1];
  const h4_t z = {(_Float16)0.f, (_Float16)0.f, (_Float16)0.f, (_Float16)0.f};
  return __builtin_elementwise_max(r, z);
}
// Build a B0 fragment from an x pair: {x0, x1, 1, 0}.
static __device__ __forceinline__ h4_t make_b0(const float* __restrict__ p) {
  const float2 xv = *(const float2*)p;
  const hp2_t xh = __builtin_amdgcn_cvt_pkrtz(xv.x, xv.y);
  h4_t b;
  b[0] = (_Float16)xh[0]; b[1] = (_Float16)xh[1];
  b[2] = (_Float16)1.0f;  b[3] = (_Float16)0.0f;
  return b;
}
// One tower's full 4-layer chain for one 16-sample tile; returns the
// lane's L3 output (only row 0 / reg 0 nonzero; other lanes return 0).
static __device__ __forceinline__ float tower_chain(
    h4_t a0, h4_t a1, h4_t a2, h4_t a3, f4_t c1, f4_t c2, h4_t b0) {
  const f4_t zc = {0.f, 0.f, 0.f, 0.f};
  const f4_t d0 = __builtin_amdgcn_mfma_f32_16x16x16f16(a0, b0, zc, 0, 0, 0);
  const h4_t h0 = relu_pack4(d0);
  const f4_t d1 = __builtin_amdgcn_mfma_f32_16x16x16f16(a1, h0, c1, 0, 0, 0);
  const h4_t h1 = relu_pack4(d1);
  const f4_t d2 = __builtin_amdgcn_mfma_f32_16x16x16f16(a2, h1, c2, 0, 0, 0);
  const h4_t h2 = relu_pack4(d2);
  const f4_t d3 = __builtin_amdgcn_mfma_f32_16x16x16f16(a3, h2, zc, 0, 0, 0);
  return d3[0];
}

__global__ void pack_frags(
    const float* __restrict__ W0, const float* __restrict__ B0,
    const float* __restrict__ W1, const float* __restrict__ B1,
    const float* __restrict__ W2, const float* __restrict__ B2,
    const float* __restrict__ W3, const float* __restrict__ B3,
    const float* __restrict__ bias, uint32_t* __restrict__ pack,
    float* __restrict__ out) {
  const int t   = blockIdx.x;
  const int l   = threadIdx.x;      // 64 threads = 64 lanes
  const int row = l & 15;           // A-frag row  = lane&15
  const int kg  = l >> 4;           // A-frag k    = (lane>>4)*4 + r
  uint32_t* rec = pack + t * REC;

  // Zero the output buffer (out[0:BATCH] accumulated by atomics;
  // shape_loss[BATCH:BATCH+NTOW] stays 0). Grid-stride over all blocks.
  for (int i = t * 64 + l; i < OUTN; i += NTOW * 64) out[i] = 0.f;

  h4_t a0, a1, a2, a3;
#pragma unroll
  for (int r = 0; r < 4; ++r) {
    const int k = kg * 4 + r;
    // A0: tower t occupies k-columns 4*(t&3) .. 4*(t&3)+2.
    float v0 = 0.f;
    if (kg == (t & 3)) {
      if (r < 2)       v0 = W0[(16*t + row) * FEAT + 2*t + r];
      else if (r == 2) v0 = B0[16*t + row];
    }
    a0[r] = (_Float16)v0;

    float v1 = 0.f;
    if (row < 12)    v1 = W1[(12*t + row) * (16*NTOW) + 16*t + k];
    a1[r] = (_Float16)v1;

    float v2 = 0.f;
    if (row < 8 && k < 12) v2 = W2[(8*t + row) * (12*NTOW) + 12*t + k];
    a2[r] = (_Float16)v2;

    float v3 = 0.f;
    if (row == 0 && k < 8) v3 = W3[t * (8*NTOW) + 8*t + k];
    a3[r] = (_Float16)v3;
  }
  uint32_t* lrec = rec + 8 * l;
  h4_to_u2(a0, lrec + 0);
  h4_to_u2(a1, lrec + 2);
  h4_to_u2(a2, lrec + 4);
  h4_to_u2(a3, lrec + 6);

  if (l < 16) {
    const float b1v = (l < 12) ? B1[12*t + l] : 0.f;
    rec[OFF_B1 + l] = __float_as_uint(b1v);
    const float b2v = (l < 8) ? B2[8*t + l] : 0.f;
    rec[OFF_B2 + l] = __float_as_uint(b2v);
  }
  if (t == 0 && l == 0) {
    float s = bias[0];
    for (int j = 0; j < NTOW; ++j) s += B3[j];
    pack[NTOW * REC] = __float_as_uint(s);
  }
}

// One block: tower group g (16 towers) x 256 samples (4 waves x 64).
// All 4 waves stream the SAME 16 tower records -> L1-resident weights.
__global__ __launch_bounds__(256, 4) void bs_mfma(
    const float* __restrict__ x, const uint32_t* __restrict__ pack,
    float* __restrict__ out) {
  const int warp  = threadIdx.x >> 6;
  const int lane  = threadIdx.x & 63;
  const int col   = lane & 15;       // sample within tile
  const int kg    = lane >> 4;
  const int g     = blockIdx.x & 7;  // tower group: towers [16g, 16g+16)
  const int tile  = blockIdx.x >> 3;
  const int sbase = tile * 256 + warp * 64;

  const float cbias = __uint_as_float(pack[NTOW * REC]);

  // Per-lane x base: sample row (sbase+col), feature 2*(16g + kg).
  const float* __restrict__ xb =
      x + (size_t)(sbase + col) * FEAT + 2 * (g * 16 + kg);

  const uint32_t* __restrict__ fp  = pack + (size_t)(g * 16) * REC + 8 * lane;
  const uint32_t* __restrict__ bp1 = pack + (size_t)(g * 16) * REC + OFF_B1 + kg * 4;
  const uint32_t* __restrict__ bp2 = pack + (size_t)(g * 16) * REC + OFF_B2 + kg * 4;

  float acc0 = 0.f, acc1 = 0.f, acc2 = 0.f, acc3 = 0.f;

#pragma unroll 1
  for (int p = 0; p < 4; ++p) {      // packs of 4 towers — ROLLED
    // Named B0 fragments for this pack's 4 sample tiles (shared by the
    // pack's 4 towers). Named scalars -> guaranteed register allocation.
    const float* __restrict__ xp = xb + 8 * p;
    const h4_t bq0 = make_b0(xp + (size_t)0 * 16 * FEAT);
    const h4_t bq1 = make_b0(xp + (size_t)1 * 16 * FEAT);
    const h4_t bq2 = make_b0(xp + (size_t)2 * 16 * FEAT);
    const h4_t bq3 = make_b0(xp + (size_t)3 * 16 * FEAT);

    const uint32_t* __restrict__ fpp  = fp  + (size_t)(4 * p) * REC;
    const uint32_t* __restrict__ bpp1 = bp1 + (size_t)(4 * p) * REC;
    const uint32_t* __restrict__ bpp2 = bp2 + (size_t)(4 * p) * REC;

#pragma unroll
    for (int jj = 0; jj < 4; ++jj) { // towers within pack — UNROLLED
      const uint4  w01 = *(const uint4*)(fpp + jj * REC);      // a0|a1
      const uint4  w23 = *(const uint4*)(fpp + jj * REC + 4);  // a2|a3
      const float4 bb1 = *(const float4*)(bpp1 + jj * REC);
      const float4 bb2 = *(const float4*)(bpp2 + jj * REC);

      const h4_t a0 = u2_to_h4(w01.x, w01.y);
      const h4_t a1 = u2_to_h4(w01.z, w01.w);
      const h4_t a2 = u2_to_h4(w23.x, w23.y);
      const h4_t a3 = u2_to_h4(w23.z, w23.w);
      const f4_t c1 = {bb1.x, bb1.y, bb1.z, bb1.w};
      const f4_t c2 = {bb2.x, bb2.y, bb2.z, bb2.w};

      acc0 += tower_chain(a0, a1, a2, a3, c1, c2, bq0);
      acc1 += tower_chain(a0, a1, a2, a3, c1, c2, bq1);
      acc2 += tower_chain(a0, a1, a2, a3, c1, c2, bq2);
      acc3 += tower_chain(a0, a1, a2, a3, c1, c2, bq3);
    }
  }

  if (kg == 0) {
    const float add = (g == 0) ? cbias : 0.f;
    atomicAdd(out + sbase +  0 + col, acc0 + add);
    atomicAdd(out + sbase + 16 + col, acc1 + add);
    atomicAdd(out + sbase + 32 + col, acc2 + add);
    atomicAdd(out + sbase + 48 + col, acc3 + add);
  }
}

// ---- correctness-only fallback (ws too small; never expected) ----
__device__ __forceinline__ float gather_weight(
    int t, int i,
    const float* __restrict__ W0, const float* __restrict__ B0,
    const float* __restrict__ W1, const float* __restrict__ B1,
    const float* __restrict__ W2, const float* __restrict__ B2,
    const float* __restrict__ W3, const float* __restrict__ B3) {
  float v = 0.f;
  if (i < 32)       { int r = i >> 1, c = i & 1;               v = W0[(16*t + r)*FEAT + 2*t + c]; }
  else if (i < 48)  {                                           v = B0[16*t + (i - 32)]; }
  else if (i < 240) { int k = i - 48, r = k >> 4, c = k & 15;   v = W1[(12*t + r)*(16*NTOW) + 16*t + c]; }
  else if (i < 252) {                                           v = B1[12*t + (i - 240)]; }
  else if (i < 348) { int k = i - 252, r = k / 12, c = k - 12*r; v = W2[(8*t + r)*(12*NTOW) + 12*t + c]; }
  else if (i < 356) {                                           v = B2[8*t + (i - 348)]; }
  else if (i < 364) {                                           v = W3[t*(8*NTOW) + 8*t + (i - 356)]; }
  else if (i == 364){                                           v = B3[t]; }
  return v;
}

__global__ void bs_fwd_slow(
    const float* __restrict__ x,
    const float* __restrict__ W0, const float* __restrict__ B0,
    const float* __restrict__ W1, const float* __restrict__ B1,
    const float* __restrict__ W2, const float* __restrict__ B2,
    const float* __restrict__ W3, const float* __restrict__ B3,
    const float* __restrict__ bias,
    float* __restrict__ out) {
  const int s = blockIdx.x * blockDim.x + threadIdx.x;
  if (s >= BATCH) return;
  float acc = bias[0];
  for (int t = 0; t < NTOW; ++t) {
    float h0[16], h1[12], h2[8];
    const float x0 = x[(size_t)s*FEAT + 2*t], x1 = x[(size_t)s*FEAT + 2*t + 1];
    for (int r = 0; r < 16; ++r)
      h0[r] = fmaxf(0.f, gather_weight(t, 2*r, W0,B0,W1,B1,W2,B2,W3,B3) * x0
                        + gather_weight(t, 2*r+1, W0,B0,W1,B1,W2,B2,W3,B3) * x1
                        + gather_weight(t, 32+r, W0,B0,W1,B1,W2,B2,W3,B3));
    for (int r = 0; r < 12; ++r) {
      float sum = gather_weight(t, 240+r, W0,B0,W1,B1,W2,B2,W3,B3);
      for (int c = 0; c < 16; ++c)
        sum += gather_weight(t, 48+16*r+c, W0,B0,W1,B1,W2,B2,W3,B3) * h0[c];
      h1[r] = fmaxf(0.f, sum);
    }
    for (int r = 0; r < 8; ++r) {
      float sum = gather_weight(t, 348+r, W0,B0,W1,B1,W2,B2,W3,B3);
      for (int c = 0; c < 12; ++c)
        sum += gather_weight(t, 252+12*r+c, W0,B0,W1,B1,W2,B2,W3,B3) * h1[c];
      h2[r] = fmaxf(0.f, sum);
    }
    float sum = gather_weight(t, 364, W0,B0,W1,B1,W2,B2,W3,B3);
    for (int c = 0; c < 8; ++c)
      sum += gather_weight(t, 356+c, W0,B0,W1,B1,W2,B2,W3,B3) * h2[c];
    acc += sum;
  }
  out[s] = acc;
}

extern "C" void kernel_launch(void* const* d_in, const int* in_sizes, int n_in,
                              void* d_out, int out_size, void* d_ws, size_t ws_size,
                              hipStream_t stream) {
  const float* x    = (const float*)d_in[0];
  const float* W0   = (const float*)d_in[1];
  const float* B0   = (const float*)d_in[2];
  const float* W1   = (const float*)d_in[3];
  const float* B1   = (const float*)d_in[4];
  const float* W2   = (const float*)d_in[5];
  const float* B2   = (const float*)d_in[6];
  const float* W3   = (const float*)d_in[7];
  const float* B3   = (const float*)d_in[8];
  const float* bias = (const float*)d_in[9];
  float* out = (float*)d_out;

  const size_t packBytes = ((size_t)NTOW * REC + 1) * sizeof(uint32_t);

  if (ws_size >= packBytes) {
    uint32_t* pack = (uint32_t*)d_ws;
    // pack_frags also zeroes out[] (atomics accumulate; shape_loss stays 0).
    pack_frags<<<NTOW, 64, 0, stream>>>(W0, B0, W1, B1, W2, B2, W3, B3, bias, pack, out);
    const int blocks = (BATCH / 256) * 8;         // 1024 blocks
    bs_mfma<<<blocks, 256, 0, stream>>>(x, pack, out);
  } else {
    (void)hipMemsetAsync(d_out, 0, (size_t)out_size * sizeof(float), stream);
    bs_fwd_slow<<<BATCH / 256, 256, 0, stream>>>(x, W0, B0, W1, B1, W2, B2, W3, B3, bias, out);
  }
}